// Round 3
// baseline (385.528 us; speedup 1.0000x reference)
//
#include <hip/hip_runtime.h>
#include <math.h>

#define RADIUS 0.05f

// --- Kernel 1: init best-distance bits to +inf (harness poisons d_out to 0xAA) ---
__global__ void init_best(unsigned int* __restrict__ best, int M) {
    int i = blockIdx.x * blockDim.x + threadIdx.x;
    if (i < M) best[i] = 0x7F800000u;  // +inf bits
}

// --- Kernel 2: pack pcd -> {-2p0, -2p1, -2p2, |p|^2} so inner loop is 3 fma + 1 min ---
__global__ void pack_pcd(const float* __restrict__ pcd, float4* __restrict__ pp, int N) {
    int j = blockIdx.x * blockDim.x + threadIdx.x;
    if (j < N) {
        float p0 = pcd[3 * j + 0];
        float p1 = pcd[3 * j + 1];
        float p2 = pcd[3 * j + 2];
        pp[j] = make_float4(-2.0f * p0, -2.0f * p1, -2.0f * p2,
                            p0 * p0 + p1 * p1 + p2 * p2);
    }
}

// --- Kernel 3: brute-force 1-NN. One thread per query, pcd split across grid.y
// segments for occupancy (8 waves/SIMD). pp[j] is wave-uniform -> one cache-hit
// 16B load per wave-point on the VMEM pipe, concurrent with VALU.
// d = |x|^2 + min_j(|p|^2 - 2 x.p) ; |x|^2 folded in once per segment.
// 4 independent min accumulators break the loop-carried v_min chain (exact:
// min-reduction order doesn't affect the result).
__global__ __launch_bounds__(256) void nn_min(const float* __restrict__ x,
                                              const float4* __restrict__ pp,
                                              unsigned int* __restrict__ best,
                                              int M, int N, int seg_len) {
    int q = blockIdx.x * 256 + threadIdx.x;
    int j0 = blockIdx.y * seg_len;
    int j1 = j0 + seg_len;
    if (j1 > N) j1 = N;

    float x0 = 0.f, x1 = 0.f, x2 = 0.f;
    if (q < M) {
        x0 = x[3 * q + 0];
        x1 = x[3 * q + 1];
        x2 = x[3 * q + 2];
    }

    float e0 = INFINITY, e1 = INFINITY, e2 = INFINITY, e3 = INFINITY;
    int j = j0;
    for (; j + 4 <= j1; j += 4) {
        float4 pa = pp[j + 0];
        float4 pb = pp[j + 1];
        float4 pc = pp[j + 2];
        float4 pd = pp[j + 3];
        e0 = fminf(e0, fmaf(pa.x, x0, fmaf(pa.y, x1, fmaf(pa.z, x2, pa.w))));
        e1 = fminf(e1, fmaf(pb.x, x0, fmaf(pb.y, x1, fmaf(pb.z, x2, pb.w))));
        e2 = fminf(e2, fmaf(pc.x, x0, fmaf(pc.y, x1, fmaf(pc.z, x2, pc.w))));
        e3 = fminf(e3, fmaf(pd.x, x0, fmaf(pd.y, x1, fmaf(pd.z, x2, pd.w))));
    }
    for (; j < j1; ++j) {
        float4 p = pp[j];
        e0 = fminf(e0, fmaf(p.x, x0, fmaf(p.y, x1, fmaf(p.z, x2, p.w))));
    }
    float emin = fminf(fminf(e0, e1), fminf(e2, e3));

    if (q < M) {
        float xs = fmaf(x0, x0, fmaf(x1, x1, x2 * x2));
        float d = fmaxf(xs + emin, 0.0f);  // clamp rounding-negative to 0
        // nonneg floats: uint bit order == float order
        atomicMin(best + q, __float_as_uint(d));
    }
}

// --- Kernel 4: finalize in-place: out = (sqrt(d) - R) * signs ---
__global__ void finalize(unsigned int* __restrict__ bits,
                         const float* __restrict__ signs,
                         float* __restrict__ out, int M) {
    int i = blockIdx.x * blockDim.x + threadIdx.x;
    if (i < M) {
        float d = __uint_as_float(bits[i]);
        out[i] = (sqrtf(d) - RADIUS) * signs[i];
    }
}

extern "C" void kernel_launch(void* const* d_in, const int* in_sizes, int n_in,
                              void* d_out, int out_size, void* d_ws, size_t ws_size,
                              hipStream_t stream) {
    const float* x     = (const float*)d_in[0];
    const float* pcd   = (const float*)d_in[1];
    const float* signs = (const float*)d_in[2];
    float* out = (float*)d_out;

    int M = in_sizes[0] / 3;
    int N = in_sizes[1] / 3;

    float4* pp = (float4*)d_ws;  // N * 16 B = 512 KB scratch

    init_best<<<(M + 255) / 256, 256, 0, stream>>>((unsigned int*)d_out, M);
    pack_pcd<<<(N + 255) / 256, 256, 0, stream>>>(pcd, pp, N);

    const int NSEG = 8;  // 8 waves/SIMD on the main kernel
    int seg_len = (N + NSEG - 1) / NSEG;
    dim3 grid((M + 255) / 256, NSEG);
    nn_min<<<grid, 256, 0, stream>>>(x, pp, (unsigned int*)d_out, M, N, seg_len);

    finalize<<<(M + 255) / 256, 256, 0, stream>>>((unsigned int*)d_out, signs, out, M);
}

// Round 4
// 298.481 us; speedup vs baseline: 1.2916x; 1.2916x over previous
//
#include <hip/hip_runtime.h>
#include <math.h>

#define RADIUS 0.05f
#define QPT 4     // queries per thread (register blocking)
#define NSEG 32   // pcd segments (grid.y) -> 2048 blocks = 8 waves/SIMD

// --- Kernel 1: init best-distance bits to +inf (harness poisons d_out to 0xAA) ---
__global__ void init_best(unsigned int* __restrict__ best, int M) {
    int i = blockIdx.x * blockDim.x + threadIdx.x;
    if (i < M) best[i] = 0x7F800000u;  // +inf bits
}

// --- Kernel 2: pack pcd -> {-2p0, -2p1, -2p2, |p|^2} so inner loop is 3 fma + 1 min ---
__global__ void pack_pcd(const float* __restrict__ pcd, float4* __restrict__ pp, int N) {
    int j = blockIdx.x * blockDim.x + threadIdx.x;
    if (j < N) {
        float p0 = pcd[3 * j + 0];
        float p1 = pcd[3 * j + 1];
        float p2 = pcd[3 * j + 2];
        pp[j] = make_float4(-2.0f * p0, -2.0f * p1, -2.0f * p2,
                            p0 * p0 + p1 * p1 + p2 * p2);
    }
}

// --- Kernel 3: brute-force 1-NN, Q=4 queries per thread.
// pp[j] is wave-uniform (scalar loads, r3 evidence: VGPR=12/SGPR=48); per point:
// 1 v_mov (p.w) shared across queries + 4x(3 v_fma + 1 v_min) = 4.25 VALU/query-point.
// d = |x|^2 + min_j(|p|^2 - 2 x.p); |x|^2 folded in once per segment.
__global__ __launch_bounds__(256) void nn_min4(const float* __restrict__ x,
                                               const float4* __restrict__ pp,
                                               unsigned int* __restrict__ best,
                                               int M, int N, int seg_len, int qstride) {
    int t = blockIdx.x * 256 + threadIdx.x;
    int j0 = blockIdx.y * seg_len;
    int j1 = j0 + seg_len;
    if (j1 > N) j1 = N;

    int qid[QPT];
    float xq0[QPT], xq1[QPT], xq2[QPT];
#pragma unroll
    for (int k = 0; k < QPT; ++k) {
        qid[k] = t + k * qstride;
        bool ok = (qid[k] < M);
        int b = ok ? 3 * qid[k] : 0;
        xq0[k] = ok ? x[b + 0] : 0.f;
        xq1[k] = ok ? x[b + 1] : 0.f;
        xq2[k] = ok ? x[b + 2] : 0.f;
    }

    float e[QPT];
#pragma unroll
    for (int k = 0; k < QPT; ++k) e[k] = INFINITY;

#pragma unroll 2
    for (int j = j0; j < j1; ++j) {
        float4 p = pp[j];  // wave-uniform address -> scalar load
        float w = p.w;     // single SGPR->VGPR mov, shared by all queries
#pragma unroll
        for (int k = 0; k < QPT; ++k) {
            float d = fmaf(p.x, xq0[k], fmaf(p.y, xq1[k], fmaf(p.z, xq2[k], w)));
            e[k] = fminf(e[k], d);
        }
    }

#pragma unroll
    for (int k = 0; k < QPT; ++k) {
        if (qid[k] < M) {
            float xs = fmaf(xq0[k], xq0[k], fmaf(xq1[k], xq1[k], xq2[k] * xq2[k]));
            float d = fmaxf(xs + e[k], 0.0f);  // clamp rounding-negative to 0
            // nonneg floats: uint bit order == float order
            atomicMin(best + qid[k], __float_as_uint(d));
        }
    }
}

// --- Kernel 4: finalize in-place: out = (sqrt(d) - R) * signs ---
__global__ void finalize(unsigned int* __restrict__ bits,
                         const float* __restrict__ signs,
                         float* __restrict__ out, int M) {
    int i = blockIdx.x * blockDim.x + threadIdx.x;
    if (i < M) {
        float d = __uint_as_float(bits[i]);
        out[i] = (sqrtf(d) - RADIUS) * signs[i];
    }
}

extern "C" void kernel_launch(void* const* d_in, const int* in_sizes, int n_in,
                              void* d_out, int out_size, void* d_ws, size_t ws_size,
                              hipStream_t stream) {
    const float* x     = (const float*)d_in[0];
    const float* pcd   = (const float*)d_in[1];
    const float* signs = (const float*)d_in[2];
    float* out = (float*)d_out;

    int M = in_sizes[0] / 3;
    int N = in_sizes[1] / 3;

    float4* pp = (float4*)d_ws;  // N * 16 B = 512 KB scratch

    init_best<<<(M + 255) / 256, 256, 0, stream>>>((unsigned int*)d_out, M);
    pack_pcd<<<(N + 255) / 256, 256, 0, stream>>>(pcd, pp, N);

    int qstride = (M + QPT - 1) / QPT;               // 16384
    int seg_len = (N + NSEG - 1) / NSEG;             // 1024
    dim3 grid((qstride + 255) / 256, NSEG);          // 64 x 32 = 2048 blocks
    nn_min4<<<grid, 256, 0, stream>>>(x, pp, (unsigned int*)d_out, M, N, seg_len, qstride);

    finalize<<<(M + 255) / 256, 256, 0, stream>>>((unsigned int*)d_out, signs, out, M);
}

// Round 7
// 216.905 us; speedup vs baseline: 1.7774x; 1.3761x over previous
//
#include <hip/hip_runtime.h>
#include <math.h>

#define RADIUS 0.05f
#define QPT 8     // queries per thread, processed as 4 packed float2 pairs
#define NSEG 64   // pcd segments (grid.y) -> 32 x 64 = 2048 blocks

typedef float f32x2 __attribute__((ext_vector_type(2)));

// --- Kernel 1: init best-distance bits to +inf (harness poisons d_out to 0xAA) ---
__global__ void init_best(unsigned int* __restrict__ best, int M) {
    int i = blockIdx.x * blockDim.x + threadIdx.x;
    if (i < M) best[i] = 0x7F800000u;  // +inf bits
}

// --- Kernel 2: pack pcd -> {-2p0, -2p1, -2p2, |p|^2} ---
__global__ void pack_pcd(const float* __restrict__ pcd, float4* __restrict__ pp, int N) {
    int j = blockIdx.x * blockDim.x + threadIdx.x;
    if (j < N) {
        float p0 = pcd[3 * j + 0];
        float p1 = pcd[3 * j + 1];
        float p2 = pcd[3 * j + 2];
        pp[j] = make_float4(-2.0f * p0, -2.0f * p1, -2.0f * p2,
                            p0 * p0 + p1 * p1 + p2 * p2);
    }
}

// --- Kernel 3: brute-force 1-NN, 8 queries/thread via packed dual-fp32
// (__builtin_elementwise_fma on f32x2 -> v_pk_fma_f32 on gfx90a+).
// pp[j] wave-uniform -> s_load (r4 evidence VGPR=16/SGPR=32). Per point:
// ~4 splat movs + 12 pk_fma + 8 v_min = ~3 VALU/query-point (vs 4.25 r4).
// d = |x|^2 + min_j(|p|^2 - 2 x.p); |x|^2 folded in once per segment.
__global__ __launch_bounds__(256) void nn_min8(const float* __restrict__ x,
                                               const float4* __restrict__ pp,
                                               unsigned int* __restrict__ best,
                                               int M, int N, int seg_len, int qstride) {
    int t = blockIdx.x * 256 + threadIdx.x;
    int j0 = blockIdx.y * seg_len;
    int j1 = j0 + seg_len;
    if (j1 > N) j1 = N;

    int qid[QPT];
    f32x2 X0[4], X1[4], X2[4], E[4];
#pragma unroll
    for (int r = 0; r < 4; ++r) {
        int q0 = t + (2 * r) * qstride;
        int q1 = t + (2 * r + 1) * qstride;
        qid[2 * r] = q0;
        qid[2 * r + 1] = q1;
        bool ok0 = q0 < M, ok1 = q1 < M;
        int b0 = ok0 ? 3 * q0 : 0;
        int b1 = ok1 ? 3 * q1 : 0;
        X0[r] = (f32x2){ok0 ? x[b0 + 0] : 0.f, ok1 ? x[b1 + 0] : 0.f};
        X1[r] = (f32x2){ok0 ? x[b0 + 1] : 0.f, ok1 ? x[b1 + 1] : 0.f};
        X2[r] = (f32x2){ok0 ? x[b0 + 2] : 0.f, ok1 ? x[b1 + 2] : 0.f};
        E[r] = (f32x2){INFINITY, INFINITY};
    }

#pragma unroll 2
    for (int j = j0; j < j1; ++j) {
        float4 p = pp[j];             // uniform address -> scalar load
        f32x2 px2 = {p.x, p.x};       // splats; allocator picks SGPR-pair or v_mov
        f32x2 py2 = {p.y, p.y};
        f32x2 pz2 = {p.z, p.z};
        f32x2 w2  = {p.w, p.w};
#pragma unroll
        for (int r = 0; r < 4; ++r) {
            // d = px*x0 + py*x1 + pz*x2 + w, two queries per instruction
            f32x2 d0 = __builtin_elementwise_fma(pz2, X2[r], w2);
            f32x2 d1 = __builtin_elementwise_fma(py2, X1[r], d0);
            f32x2 d2 = __builtin_elementwise_fma(px2, X0[r], d1);
            E[r].x = fminf(E[r].x, d2.x);
            E[r].y = fminf(E[r].y, d2.y);
        }
    }

#pragma unroll
    for (int r = 0; r < 4; ++r) {
        float xs0 = fmaf(X0[r].x, X0[r].x, fmaf(X1[r].x, X1[r].x, X2[r].x * X2[r].x));
        float xs1 = fmaf(X0[r].y, X0[r].y, fmaf(X1[r].y, X1[r].y, X2[r].y * X2[r].y));
        if (qid[2 * r] < M) {
            float d = fmaxf(xs0 + E[r].x, 0.0f);  // nonneg: uint order == float order
            atomicMin(best + qid[2 * r], __float_as_uint(d));
        }
        if (qid[2 * r + 1] < M) {
            float d = fmaxf(xs1 + E[r].y, 0.0f);
            atomicMin(best + qid[2 * r + 1], __float_as_uint(d));
        }
    }
}

// --- Kernel 4: finalize in-place: out = (sqrt(d) - R) * signs ---
__global__ void finalize(unsigned int* __restrict__ bits,
                         const float* __restrict__ signs,
                         float* __restrict__ out, int M) {
    int i = blockIdx.x * blockDim.x + threadIdx.x;
    if (i < M) {
        float d = __uint_as_float(bits[i]);
        out[i] = (sqrtf(d) - RADIUS) * signs[i];
    }
}

extern "C" void kernel_launch(void* const* d_in, const int* in_sizes, int n_in,
                              void* d_out, int out_size, void* d_ws, size_t ws_size,
                              hipStream_t stream) {
    const float* x     = (const float*)d_in[0];
    const float* pcd   = (const float*)d_in[1];
    const float* signs = (const float*)d_in[2];
    float* out = (float*)d_out;

    int M = in_sizes[0] / 3;
    int N = in_sizes[1] / 3;

    float4* pp = (float4*)d_ws;  // N * 16 B = 512 KB scratch

    init_best<<<(M + 255) / 256, 256, 0, stream>>>((unsigned int*)d_out, M);
    pack_pcd<<<(N + 255) / 256, 256, 0, stream>>>(pcd, pp, N);

    int qstride = (M + QPT - 1) / QPT;        // 8192
    int seg_len = (N + NSEG - 1) / NSEG;      // 512
    dim3 grid((qstride + 255) / 256, NSEG);   // 32 x 64 = 2048 blocks
    nn_min8<<<grid, 256, 0, stream>>>(x, pp, (unsigned int*)d_out, M, N, seg_len, qstride);

    finalize<<<(M + 255) / 256, 256, 0, stream>>>((unsigned int*)d_out, signs, out, M);
}